// Round 17
// baseline (779.802 us; speedup 1.0000x reference)
//
#include <hip/hip_runtime.h>
#include <math.h>

// ---------------------------------------------------------------------------
// SACNet forward. conv0/1/2 = round-6 split-bf16 MFMA (measured best);
// d1 GEMM = A-bf16 x W-bf16 MFMA, 64x128 tiles; fused attn/VQ chain.
// B=512, IN=200, P=19, CF=64, TF=32, K=48, D=32, NC=16
// ---------------------------------------------------------------------------

typedef __attribute__((ext_vector_type(8))) short short8v;   // 8 bf16
typedef __attribute__((ext_vector_type(4))) float f32x4;

// workspace offsets (in floats)
#define OFF_WE1H  188928u      // 4734976 shorts = 2367488 floats
#define OFF_WE2H  4923904u
#define OFF_WE3H  7692800u
#define OFF_C1    8495616u     // 512*64*289 (TMP aliases this while building weff)
#define OFF_C2    17965568u    // 512*64*169
#define OFF_XX1   23503360u    // 512*64*49
#define OFF_ALPHA 25108992u    // (conv weights alias pre-abg; H1P at dense phase)
#define OFF_BETA  25911808u    // (MS aliases this after sac_abgctx)
#define OFF_GAM   26714624u
#define OFF_CTX   27517440u    // 512*2401
#define OFF_CTX2  28746752u
#define OFF_XX2   29549568u    // 512*3136
#define OFF_Z     31155200u
#define OFF_A     31958016u
#define OFF_E     33162240u
#define OFF_BNS   33948672u
#define OFF_XX3   33948768u

// H1P: 28 x 512 x 256 = 3670016 floats at OFF_ALPHA (dense phase; dead region)
#define OFF_H1P   OFF_ALPHA
// MS (softmax stats 2x2401) at OFF_BETA (dead before d1gemm)
#define OFF_MS    OFF_BETA

// conv weights (round-6 layout):
#define OFF_WH    OFF_ALPHA
#define OFF_WL    (OFF_ALPHA + 64512u)
#define OFF_W1H   (OFF_ALPHA + 129024u)
#define OFF_W1L   (OFF_W1H + 18432u)
#define OFF_W2H   (OFF_W1L + 18432u)
#define OFF_W2L   (OFF_W2H + 18432u)
// ends 25311744 < OFF_BETA. All dead before sac_abgctx.

__device__ __forceinline__ unsigned bf16_rne_bits(float v) {
    unsigned u = __float_as_uint(v);
    return (u + 0x7FFFu + ((u >> 16) & 1u)) >> 16;
}

// -------------------- split w0 into bf16 hi/lo [s][c][224] -----------------
__global__ __launch_bounds__(256) void sac_wsplit(const float* __restrict__ w0,
                                                  unsigned short* __restrict__ WH,
                                                  unsigned short* __restrict__ WL) {
    int idx = blockIdx.x * 256 + threadIdx.x;   // 9*64*224 = 129024
    if (idx >= 129024) return;
    int ic = idx % 224;
    int c  = (idx / 224) % 64;
    int s  = idx / (224 * 64);
    int ky = s / 3, kx = s % 3;
    float v = 0.f;
    if (ic < 200) v = w0[((c * 200 + ic) * 3 + ky) * 3 + kx];
    unsigned hb = bf16_rne_bits(v);
    float hf = __uint_as_float(hb << 16);
    unsigned lb = bf16_rne_bits(v - hf);
    WH[idx] = (unsigned short)hb;
    WL[idx] = (unsigned short)lb;
}

// -------------------- split 64x64x3x3 weights into [s][c][64] --------------
__global__ __launch_bounds__(256) void sac_wsplit64(const float* __restrict__ wsrc,
                                                    unsigned short* __restrict__ WHo,
                                                    unsigned short* __restrict__ WLo) {
    int idx = blockIdx.x * 256 + threadIdx.x;   // 36864
    if (idx >= 36864) return;
    int ic = idx & 63;
    int c  = (idx >> 6) & 63;
    int s  = idx >> 12;
    int ky = s / 3, kx = s - ky * 3;
    float v = wsrc[((c * 64 + ic) * 3 + ky) * 3 + kx];
    unsigned hb = bf16_rne_bits(v);
    float hf = __uint_as_float(hb << 16);
    unsigned lb = bf16_rne_bits(v - hf);
    WHo[idx] = (unsigned short)hb;
    WLo[idx] = (unsigned short)lb;
}

// --------------------- fold bilinear upsample into w_d1 --------------------
// Sparse inner range (skipped terms exact zeros -> bitwise identical).
__global__ __launch_bounds__(256) void sac_upA(const float* __restrict__ w_d1,
                                               float* __restrict__ tmp, int S, int co) {
    int idx = blockIdx.x * 256 + threadIdx.x;
    int total = 256 * 64 * 19 * S;
    if (idx >= total) return;
    int xp = idx % S;
    int j  = (idx / S) % 19;
    int c  = (idx / (S * 19)) % 64;
    int o  = idx / (S * 19 * 64);
    const float* wrow = w_d1 + (size_t)o * 69312 + (size_t)(co + c) * 361 + j * 19;
    float ratio = (float)(S - 1) / 18.0f;
    int ilo = ((xp - 1) * 18) / (S - 1) - 1; if (ilo < 0) ilo = 0;
    int ihi = ((xp + 1) * 18) / (S - 1) + 1; if (ihi > 18) ihi = 18;
    float s = 0.f;
    for (int i = ilo; i <= ihi; ++i) {
        float xs = i * ratio;
        int x0 = (int)floorf(xs);
        float wx = xs - (float)x0;
        int x1 = x0 + 1; if (x1 > S - 1) x1 = S - 1;
        float cf = (xp == x0 ? 1.f - wx : 0.f) + (xp == x1 ? wx : 0.f);
        s += cf * wrow[i];
    }
    tmp[idx] = s;
}
// upB emits bf16 (hi only) weff
__global__ __launch_bounds__(256) void sac_upB_bf16(const float* __restrict__ tmp,
                                                    unsigned short* __restrict__ WEH, int S) {
    int idx = blockIdx.x * 256 + threadIdx.x;
    int total = 256 * 64 * S * S;
    if (idx >= total) return;
    int xp = idx % S;
    int yp = (idx / S) % S;
    int c  = (idx / (S * S)) % 64;
    int o  = idx / (S * S * 64);
    const float* tp = tmp + (((size_t)o * 64 + c) * 19) * S + xp;
    float ratio = (float)(S - 1) / 18.0f;
    int jlo = ((yp - 1) * 18) / (S - 1) - 1; if (jlo < 0) jlo = 0;
    int jhi = ((yp + 1) * 18) / (S - 1) + 1; if (jhi > 18) jhi = 18;
    float s = 0.f;
    for (int j = jlo; j <= jhi; ++j) {
        float ys = j * ratio;
        int y0 = (int)floorf(ys);
        float wy = ys - (float)y0;
        int y1 = y0 + 1; if (y1 > S - 1) y1 = S - 1;
        float cf = (yp == y0 ? 1.f - wy : 0.f) + (yp == y1 ? wy : 0.f);
        s += cf * tp[j * S];
    }
    WEH[idx] = (unsigned short)bf16_rne_bits(s);
}

// ---------------- generic 3x3 dilated conv, split-bf16 MFMA ----------------
// Round-6 structure (measured best).
template<int IW, int OW, int DIL, int TOTCH, int WSTR, int NMT, int NIRMAX>
__global__ __launch_bounds__(256, 4) void sac_convmfma(const float* __restrict__ x,
                                                       const unsigned short* __restrict__ WHp,
                                                       const unsigned short* __restrict__ WLp,
                                                       const float* __restrict__ bias,
                                                       float* __restrict__ out) {
    constexpr int OP = OW * OW;
    constexpr int ISZ = IW * IW;
    constexpr int NCHUNK = WSTR / 32;
    constexpr int NRC = NIRMAX * IW;
    constexpr int RB = (NRC + 31) / 32;
    __shared__ __align__(16) unsigned short XH[NRC * 32 + 64];
    __shared__ __align__(16) unsigned short XL[NRC * 32 + 64];
    int blk = blockIdx.x;
    int b = blk / NMT, mt = blk - b * NMT;
    int tid = threadIdx.x;
    int wv = tid >> 6, l = tid & 63;
    int lh = l >> 5, li = l & 31;
    int wm = wv >> 1, wn = wv & 1;
    int q = l >> 4, r = l & 15;
    int p_base = mt * 64 + wm * 32;
    int n_base = wn * 32;
    int pixA = p_base + r;      if (pixA > OP - 1) pixA = OP - 1;
    int pixB = p_base + 16 + r; if (pixB > OP - 1) pixB = OP - 1;
    int pyA = pixA / OW, pxa = pixA - pyA * OW;
    int pyB = pixB / OW, pxb = pixB - pyB * OW;
    int ir0 = (mt * 64) / OW;
    int rcA0 = (pyA - ir0) * IW + pxa;
    int rcB0 = (pyB - ir0) * IW + pxb;

    f32x4 acc[2][2];
    #pragma unroll
    for (int i = 0; i < 2; ++i)
        #pragma unroll
        for (int j = 0; j < 2; ++j) { acc[i][j].x = 0.f; acc[i][j].y = 0.f; acc[i][j].z = 0.f; acc[i][j].w = 0.f; }

    for (int cc = 0; cc < NCHUNK; ++cc) {
        int ch0 = cc * 32;
        __syncthreads();
        for (int it = wv; it < 4 * RB; it += 4) {
            int cg = it / RB, rb = it - cg * RB;
            int rc = rb * 32 + li;
            if (rc < NRC) {
                int chl4 = cg * 2 + lh;          // 0..7
                int ch = ch0 + chl4 * 4;
                int idx = ir0 * IW + rc; if (idx > ISZ - 1) idx = ISZ - 1;
                const float* gp = x + (size_t)b * (TOTCH * ISZ) + (size_t)ch * ISZ + idx;
                float v0 = (ch + 0 < TOTCH) ? gp[0] : 0.f;
                float v1 = (ch + 1 < TOTCH) ? gp[ISZ] : 0.f;
                float v2 = (ch + 2 < TOTCH) ? gp[2 * ISZ] : 0.f;
                float v3 = (ch + 3 < TOTCH) ? gp[3 * ISZ] : 0.f;
                unsigned h0 = bf16_rne_bits(v0); unsigned l0 = bf16_rne_bits(v0 - __uint_as_float(h0 << 16));
                unsigned h1 = bf16_rne_bits(v1); unsigned l1 = bf16_rne_bits(v1 - __uint_as_float(h1 << 16));
                unsigned h2 = bf16_rne_bits(v2); unsigned l2 = bf16_rne_bits(v2 - __uint_as_float(h2 << 16));
                unsigned h3 = bf16_rne_bits(v3); unsigned l3 = bf16_rne_bits(v3 - __uint_as_float(h3 << 16));
                unsigned bo = ((unsigned)(rc * 64 + chl4 * 8)) ^ (unsigned)((rc & 7) << 4);
                uint2 hv; hv.x = h0 | (h1 << 16); hv.y = h2 | (h3 << 16);
                uint2 lv; lv.x = l0 | (l1 << 16); lv.y = l2 | (l3 << 16);
                *(uint2*)((char*)XH + bo) = hv;
                *(uint2*)((char*)XL + bo) = lv;
            }
        }
        __syncthreads();
        #pragma unroll 3
        for (int s9 = 0; s9 < 9; ++s9) {
            int ky = s9 / 3, kx = s9 - ky * 3;
            int rcA = rcA0 + DIL * (ky * IW + kx);
            int rcB = rcB0 + DIL * (ky * IW + kx);
            unsigned byA = ((unsigned)(rcA * 64 + q * 16)) ^ (unsigned)((rcA & 7) << 4);
            unsigned byB = ((unsigned)(rcB * 64 + q * 16)) ^ (unsigned)((rcB & 7) << 4);
            short8v ah0 = *(const short8v*)((const char*)XH + byA);
            short8v al0 = *(const short8v*)((const char*)XL + byA);
            short8v ah1 = *(const short8v*)((const char*)XH + byB);
            short8v al1 = *(const short8v*)((const char*)XL + byB);
            const unsigned short* pWH = WHp + (size_t)(s9 * 64 + n_base + r) * WSTR + ch0 + q * 8;
            const unsigned short* pWL = WLp + (size_t)(s9 * 64 + n_base + r) * WSTR + ch0 + q * 8;
            short8v bh0 = *(const short8v*)(pWH);
            short8v bh1 = *(const short8v*)(pWH + 16 * WSTR);
            short8v bl0 = *(const short8v*)(pWL);
            short8v bl1 = *(const short8v*)(pWL + 16 * WSTR);
            acc[0][0] = __builtin_amdgcn_mfma_f32_16x16x32_bf16(ah0, bh0, acc[0][0], 0, 0, 0);
            acc[0][1] = __builtin_amdgcn_mfma_f32_16x16x32_bf16(ah0, bh1, acc[0][1], 0, 0, 0);
            acc[1][0] = __builtin_amdgcn_mfma_f32_16x16x32_bf16(ah1, bh0, acc[1][0], 0, 0, 0);
            acc[1][1] = __builtin_amdgcn_mfma_f32_16x16x32_bf16(ah1, bh1, acc[1][1], 0, 0, 0);
            acc[0][0] = __builtin_amdgcn_mfma_f32_16x16x32_bf16(ah0, bl0, acc[0][0], 0, 0, 0);
            acc[0][1] = __builtin_amdgcn_mfma_f32_16x16x32_bf16(ah0, bl1, acc[0][1], 0, 0, 0);
            acc[1][0] = __builtin_amdgcn_mfma_f32_16x16x32_bf16(ah1, bl0, acc[1][0], 0, 0, 0);
            acc[1][1] = __builtin_amdgcn_mfma_f32_16x16x32_bf16(ah1, bl1, acc[1][1], 0, 0, 0);
            acc[0][0] = __builtin_amdgcn_mfma_f32_16x16x32_bf16(al0, bh0, acc[0][0], 0, 0, 0);
            acc[0][1] = __builtin_amdgcn_mfma_f32_16x16x32_bf16(al0, bh1, acc[0][1], 0, 0, 0);
            acc[1][0] = __builtin_amdgcn_mfma_f32_16x16x32_bf16(al1, bh0, acc[1][0], 0, 0, 0);
            acc[1][1] = __builtin_amdgcn_mfma_f32_16x16x32_bf16(al1, bh1, acc[1][1], 0, 0, 0);
        }
    }
    float bias0 = bias[n_base + r];
    float bias1 = bias[n_base + 16 + r];
    #pragma unroll
    for (int mf = 0; mf < 2; ++mf) {
        #pragma unroll
        for (int nf = 0; nf < 2; ++nf) {
            int ch = n_base + nf * 16 + r;
            float bs = nf ? bias1 : bias0;
            float* op = out + ((size_t)b * 64 + ch) * OP;
            #pragma unroll
            for (int j = 0; j < 4; ++j) {
                int pix = p_base + mf * 16 + q * 4 + j;
                if (pix < OP) {
                    float v = acc[mf][nf][j] + bs;
                    op[pix] = v > 0.f ? v : 0.f;
                }
            }
        }
    }
}

// ------- fused: 1x1 convs a/b/g + ctx = alpha(raw reshape) @ beta ----------
__global__ __launch_bounds__(256) void sac_abgctx(const float* __restrict__ xx1,
                                                  const float* __restrict__ wa,
                                                  const float* __restrict__ wb,
                                                  const float* __restrict__ wg,
                                                  float* __restrict__ gam,
                                                  float* __restrict__ ctx) {
    int b = blockIdx.x, tid = threadIdx.x;
    __shared__ float xsm[3136];
    __shared__ float ws3[3 * 2048];
    __shared__ float ab[3136];          // alpha[0..1568) beta[1568..3136)
    for (int f = tid; f < 3136; f += 256) xsm[f] = xx1[(size_t)b * 3136 + f];
    for (int f = tid; f < 2048; f += 256) {
        ws3[f] = wa[f]; ws3[2048 + f] = wb[f]; ws3[4096 + f] = wg[f];
    }
    __syncthreads();
    for (int f = tid; f < 4704; f += 256) {
        int which = f / 1568, r = f - which * 1568;
        int t = r / 49, p = r - t * 49;
        const float* w = &ws3[which * 2048 + t * 64];
        float s = 0.f;
        #pragma unroll 8
        for (int c = 0; c < 64; ++c) s += w[c] * xsm[c * 49 + p];
        if (which == 2) {
            s = s > 0.f ? s : 0.f;
            gam[(size_t)b * 1568 + r] = s;
        } else {
            ab[which * 1568 + r] = s;
        }
    }
    __syncthreads();
    for (int f = tid; f < 2401; f += 256) {
        int i = f / 49, lcol = f - i * 49;
        float s = 0.f;
        #pragma unroll 8
        for (int j = 0; j < 32; ++j) s += ab[i * 32 + j] * ab[1568 + j * 49 + lcol];
        ctx[(size_t)b * 2401 + f] = s;
    }
}

// -------- softmax-over-batch stats: MS[pos]=max, MS[2401+pos]=1/sum --------
__global__ __launch_bounds__(256) void sac_smstat(const float* __restrict__ ctx,
                                                  float* __restrict__ ms) {
    __shared__ float red[8][32];
    int tid = threadIdx.x;
    int pl = tid & 31, g = tid >> 5;
    int pos = blockIdx.x * 32 + pl;
    bool ok = pos < 2401;
    float m = -1e30f;
    if (ok) for (int b = g; b < 512; b += 8) m = fmaxf(m, ctx[(size_t)b * 2401 + pos]);
    red[g][pl] = m;
    __syncthreads();
    if (g == 0) {
        #pragma unroll
        for (int t = 1; t < 8; ++t) m = fmaxf(m, red[t][pl]);
        red[0][pl] = m;
    }
    __syncthreads();
    m = red[0][pl];
    float s = 0.f;
    if (ok) for (int b = g; b < 512; b += 8) s += expf(ctx[(size_t)b * 2401 + pos] - m);
    __syncthreads();
    red[g][pl] = s;
    __syncthreads();
    if (g == 0 && ok) {
        #pragma unroll
        for (int t = 1; t < 8; ++t) s += red[t][pl];
        ms[pos] = m;
        ms[2401 + pos] = 1.f / s;
    }
}

// ---------------- ctx2 = gam @ softmax0(ctx) (normalize fused) -------------
__global__ __launch_bounds__(256) void sac_ctx2(const float* __restrict__ gam,
                                                const float* __restrict__ ctx,
                                                const float* __restrict__ ms,
                                                float* __restrict__ ctx2) {
    int b = blockIdx.x, tid = threadIdx.x;
    __shared__ float gs[1568];
    __shared__ float cs[2401];
    for (int f = tid; f < 1568; f += 256) gs[f] = gam[(size_t)b * 1568 + f];
    for (int f = tid; f < 2401; f += 256)
        cs[f] = expf(ctx[(size_t)b * 2401 + f] - ms[f]) * ms[2401 + f];
    __syncthreads();
    for (int f = tid; f < 1568; f += 256) {
        int t = f / 49, lcol = f - t * 49;
        float s = 0.f;
        #pragma unroll 7
        for (int i = 0; i < 49; ++i) s += gs[t * 49 + i] * cs[i * 49 + lcol];
        ctx2[(size_t)b * 1568 + f] = s;
    }
}

// -------- fused: xx2 = relu(wd @ ctx2) + xx1 ; Z = relu(wenc @ xx2) --------
__global__ __launch_bounds__(256) void sac_xx2z(const float* __restrict__ ctx2,
                                                const float* __restrict__ wd,
                                                const float* __restrict__ xx1,
                                                const float* __restrict__ wenc,
                                                float* __restrict__ xx2,
                                                float* __restrict__ Z) {
    int b = blockIdx.x, tid = threadIdx.x;
    __shared__ float cs[1568];
    __shared__ float wds[2048];
    __shared__ float xs2[3136];
    __shared__ float wt[2048];   // [c][d]
    for (int f = tid; f < 1568; f += 256) cs[f] = ctx2[(size_t)b * 1568 + f];
    for (int f = tid; f < 2048; f += 256) {
        wds[f] = wd[f];
        int d = f >> 6, c = f & 63; wt[c * 32 + d] = wenc[f];
    }
    __syncthreads();
    for (int f = tid; f < 3136; f += 256) {
        int c = f / 49, p = f - c * 49;
        float s = 0.f;
        #pragma unroll 8
        for (int t = 0; t < 32; ++t) s += wds[c * 32 + t] * cs[t * 49 + p];
        s = s > 0.f ? s : 0.f;
        s += xx1[(size_t)b * 3136 + f];
        xs2[f] = s;
        xx2[(size_t)b * 3136 + f] = s;
    }
    __syncthreads();
    for (int f = tid; f < 1568; f += 256) {
        int p = f >> 5, d = f & 31;
        float s = 0.f;
        #pragma unroll 8
        for (int c = 0; c < 64; ++c) s += wt[c * 32 + d] * xs2[c * 49 + p];
        Z[(size_t)b * 1568 + f] = s > 0.f ? s : 0.f;
    }
}

// -------------- dist + softmax over k (48), fused in-register --------------
__global__ __launch_bounds__(256) void sac_dista(const float* __restrict__ Z,
                                                 const float* __restrict__ cw,
                                                 const float* __restrict__ scale,
                                                 float* __restrict__ A) {
    __shared__ float cws[1536];
    __shared__ float c2s[48];
    __shared__ float scs[48];
    int tid = threadIdx.x;
    for (int f = tid; f < 1536; f += 256) cws[f] = cw[f];
    if (tid < 48) scs[tid] = scale[tid];
    __syncthreads();
    if (tid < 48) {
        float s = 0.f;
        for (int d = 0; d < 32; ++d) { float v = cws[tid * 32 + d]; s += v * v; }
        c2s[tid] = s;
    }
    __syncthreads();
    int idx = blockIdx.x * 256 + tid;      // (b,p) over 25088
    if (idx >= 25088) return;
    const float4* zp = (const float4*)(Z + (size_t)idx * 32);
    float zr[32];
    #pragma unroll
    for (int q = 0; q < 8; ++q) {
        float4 v = zp[q];
        zr[q * 4] = v.x; zr[q * 4 + 1] = v.y; zr[q * 4 + 2] = v.z; zr[q * 4 + 3] = v.w;
    }
    float z2 = 0.f;
    #pragma unroll
    for (int d = 0; d < 32; ++d) z2 += zr[d] * zr[d];
    float v48[48];
    float m = -1e30f;
    for (int k = 0; k < 48; ++k) {
        float dot = 0.f;
        #pragma unroll
        for (int d = 0; d < 32; ++d) dot += zr[d] * cws[k * 32 + d];
        float dv = scs[k] * (z2 + c2s[k] - 2.f * dot);
        v48[k] = dv;
        m = fmaxf(m, dv);
    }
    float s = 0.f;
    #pragma unroll
    for (int k = 0; k < 48; ++k) { v48[k] = expf(v48[k] - m); s += v48[k]; }
    float inv = 1.f / s;
    float* ap = A + (size_t)idx * 48;
    #pragma unroll
    for (int k = 0; k < 48; ++k) ap[k] = v48[k] * inv;
}

// ------------- E[b,k,d] = sum_p A*Z - (sum_p A) * C ------------------------
__global__ __launch_bounds__(256) void sac_e(const float* __restrict__ A,
                                             const float* __restrict__ Z,
                                             const float* __restrict__ cw,
                                             float* __restrict__ E) {
    int b = blockIdx.x, tid = threadIdx.x;
    __shared__ float As[2352];
    __shared__ float Zs[1568];
    __shared__ float asum[48];
    for (int f = tid; f < 2352; f += 256) As[f] = A[(size_t)b * 2352 + f];
    for (int f = tid; f < 1568; f += 256) Zs[f] = Z[(size_t)b * 1568 + f];
    __syncthreads();
    if (tid < 48) {
        float s = 0.f;
        for (int p = 0; p < 49; ++p) s += As[p * 48 + tid];
        asum[tid] = s;
    }
    __syncthreads();
    for (int f = tid; f < 1536; f += 256) {
        int k = f >> 5, d = f & 31;
        float s = 0.f;
        #pragma unroll 7
        for (int p = 0; p < 49; ++p) s += As[p * 48 + k] * Zs[p * 32 + d];
        E[(size_t)b * 1536 + f] = s - asum[k] * cw[f];
    }
}

// --------- BatchNorm stats per code k (single pass: sum + sumsq) -----------
__global__ __launch_bounds__(256) void sac_bnstat(const float* __restrict__ E,
                                                  float* __restrict__ bns) {
    int k = blockIdx.x, tid = threadIdx.x;
    __shared__ float sr[4], qr[4];
    float s = 0.f, q = 0.f;
    for (int i = tid; i < 16384; i += 256) {
        int b = i >> 5, d = i & 31;
        float v = E[((size_t)b * 48 + k) * 32 + d];
        s += v;
        q += v * v;
    }
    #pragma unroll
    for (int off = 32; off > 0; off >>= 1) {
        s += __shfl_xor(s, off, 64);
        q += __shfl_xor(q, off, 64);
    }
    int lane = tid & 63, wid = tid >> 6;
    if (lane == 0) { sr[wid] = s; qr[wid] = q; }
    __syncthreads();
    if (tid == 0) {
        float mu = (sr[0] + sr[1] + sr[2] + sr[3]) / 16384.f;
        float ms2 = (qr[0] + qr[1] + qr[2] + qr[3]) / 16384.f;
        float var = ms2 - mu * mu;
        if (var < 0.f) var = 0.f;
        bns[k] = mu;
        bns[48 + k] = rsqrtf(var + 1e-5f);
    }
}

// ---------------- BN+relu -> E_sum -> gate -> xx3 --------------------------
__global__ __launch_bounds__(256) void sac_gate(const float* __restrict__ E,
                                                const float* __restrict__ bns,
                                                const float* __restrict__ bn_g,
                                                const float* __restrict__ bn_b,
                                                const float* __restrict__ w_att,
                                                const float* __restrict__ b_att,
                                                const float* __restrict__ xx2,
                                                float* __restrict__ xx3) {
    int b = blockIdx.x, tid = threadIdx.x;
    __shared__ float esd[32];
    __shared__ float gs[64];
    if (tid < 32) {
        int d = tid;
        float s = 0.f;
        for (int k = 0; k < 48; ++k) {
            float v = (E[((size_t)b * 48 + k) * 32 + d] - bns[k]) * bns[48 + k] * bn_g[k] + bn_b[k];
            s += v > 0.f ? v : 0.f;
        }
        esd[d] = s;
    }
    __syncthreads();
    if (tid < 64) {
        int c = tid;
        float a = b_att[c];
        #pragma unroll 8
        for (int d = 0; d < 32; ++d) a += esd[d] * w_att[c * 32 + d];
        gs[c] = 1.f / (1.f + expf(-a)) + 1.f;     // 1 + gate
    }
    __syncthreads();
    for (int f = tid; f < 3136; f += 256) {
        int c = f / 49;
        xx3[(size_t)b * 3136 + f] = xx2[(size_t)b * 3136 + f] * gs[c];
    }
}

// ------- d1 GEMM: A=bf16 x W=bf16 MFMA, fine split-K, 64b x 128o tiles -----
// 448 blocks = 28 K-groups x 8 b-tiles x 2 o-tiles. Halves A re-reads (4->2)
// and W re-reads (8->4) vs 64x64: ~392 -> ~196 MB HBM. Per-output arithmetic
// identical (same K split, same k-step order) -> bitwise-identical result.
__global__ __launch_bounds__(256, 4) void sac_d1gemm_mfma(const float* __restrict__ c1,
                                                          const float* __restrict__ c2,
                                                          const float* __restrict__ xx3,
                                                          const unsigned short* __restrict__ we1h,
                                                          const unsigned short* __restrict__ we2h,
                                                          const unsigned short* __restrict__ we3h,
                                                          float* __restrict__ h1p) {
    constexpr int KCH = 128;
    __shared__ unsigned short AH[64 * KCH + 64];
    int blk = blockIdx.x;
    int g = blk >> 4, r4 = blk & 15;
    int b0 = (r4 >> 1) * 64, o0 = (r4 & 1) * 128;
    const float* Ab; const unsigned short *WHb; int astr, klen, kbase;
    if (g < 16)      { int slab = g >> 2, kq4 = g & 3;
                       Ab = c1;  WHb = we1h; astr = 18496; klen = 1156; kbase = slab * 4624 + kq4 * 1156; }
    else if (g < 24) { int gg = g - 16; int slab = gg >> 2, kq4 = gg & 3;
                       Ab = c2;  WHb = we2h; astr = 10816; klen = 1352; kbase = slab * 5408 + kq4 * 1352; }
    else             { int kq4 = g - 24;
                       Ab = xx3; WHb = we3h; astr = 3136;  klen = 784;  kbase = kq4 * 784; }
    int tid = threadIdx.x;
    int w = tid >> 6, l = tid & 63;
    int wm = w >> 1, wn = w & 1;
    int q = l >> 4, r = l & 15;

    f32x4 acc[2][4];
    #pragma unroll
    for (int i = 0; i < 2; ++i)
        #pragma unroll
        for (int j = 0; j < 4; ++j) { acc[i][j].x = 0.f; acc[i][j].y = 0.f; acc[i][j].z = 0.f; acc[i][j].w = 0.f; }

    int nkch = (klen + KCH - 1) / KCH;
    for (int kc = 0; kc < nkch; ++kc) {
        int k0 = kc * KCH;
        __syncthreads();
        for (int f = tid; f < 64 * (KCH / 2); f += 256) {
            int row = f >> 6, col2 = (f & 63) << 1;
            int kk = k0 + col2;
            float va = 0.f, vb = 0.f;
            if (kk < klen) {
                float2 v = *(const float2*)(Ab + (size_t)(b0 + row) * astr + kbase + kk);
                va = v.x; vb = v.y;
            }
            unsigned h0 = bf16_rne_bits(va);
            unsigned h1 = bf16_rne_bits(vb);
            unsigned bo = ((unsigned)(row * 256 + col2 * 2)) ^ (unsigned)((row & 7) << 4);
            *(unsigned*)((char*)AH + bo) = h0 | (h1 << 16);
        }
        __syncthreads();
        #pragma unroll
        for (int ks = 0; ks < KCH / 32; ++ks) {
            int k = ks * 32 + q * 8;
            int rowA0 = wm * 32 + r, rowA1 = wm * 32 + 16 + r;
            unsigned byA0 = ((unsigned)(rowA0 * 256 + k * 2)) ^ (unsigned)((rowA0 & 7) << 4);
            unsigned byA1 = ((unsigned)(rowA1 * 256 + k * 2)) ^ (unsigned)((rowA1 & 7) << 4);
            short8v ah0 = *(const short8v*)((const char*)AH + byA0);
            short8v ah1 = *(const short8v*)((const char*)AH + byA1);
            size_t wofs = (size_t)(o0 + wn * 64 + r) * astr + kbase + k0 + k;
            short8v bh0 = *(const short8v*)(WHb + wofs);
            short8v bh1 = *(const short8v*)(WHb + wofs + (size_t)16 * astr);
            short8v bh2 = *(const short8v*)(WHb + wofs + (size_t)32 * astr);
            short8v bh3 = *(const short8v*)(WHb + wofs + (size_t)48 * astr);
            acc[0][0] = __builtin_amdgcn_mfma_f32_16x16x32_bf16(ah0, bh0, acc[0][0], 0, 0, 0);
            acc[0][1] = __builtin_amdgcn_mfma_f32_16x16x32_bf16(ah0, bh1, acc[0][1], 0, 0, 0);
            acc[0][2] = __builtin_amdgcn_mfma_f32_16x16x32_bf16(ah0, bh2, acc[0][2], 0, 0, 0);
            acc[0][3] = __builtin_amdgcn_mfma_f32_16x16x32_bf16(ah0, bh3, acc[0][3], 0, 0, 0);
            acc[1][0] = __builtin_amdgcn_mfma_f32_16x16x32_bf16(ah1, bh0, acc[1][0], 0, 0, 0);
            acc[1][1] = __builtin_amdgcn_mfma_f32_16x16x32_bf16(ah1, bh1, acc[1][1], 0, 0, 0);
            acc[1][2] = __builtin_amdgcn_mfma_f32_16x16x32_bf16(ah1, bh2, acc[1][2], 0, 0, 0);
            acc[1][3] = __builtin_amdgcn_mfma_f32_16x16x32_bf16(ah1, bh3, acc[1][3], 0, 0, 0);
        }
    }
    #pragma unroll
    for (int mf = 0; mf < 2; ++mf) {
        #pragma unroll
        for (int nf = 0; nf < 4; ++nf) {
            int o = o0 + wn * 64 + nf * 16 + r;
            #pragma unroll
            for (int j = 0; j < 4; ++j) {
                int batch = b0 + wm * 32 + mf * 16 + q * 4 + j;
                h1p[((size_t)g * 512 + batch) * 256 + o] = acc[mf][nf][j];
            }
        }
    }
}

// ----- fused head: h1 = relu(sum 28 partials + b1); h2 = relu(.); out ------
__global__ __launch_bounds__(256) void sac_head(const float* __restrict__ h1p,
                                                const float* __restrict__ b_d1,
                                                const float* __restrict__ w_d2,
                                                const float* __restrict__ b_d2,
                                                const float* __restrict__ w_d3,
                                                const float* __restrict__ b_d3,
                                                float* __restrict__ out) {
    int b = blockIdx.x, tid = threadIdx.x;
    __shared__ float h1s[256];
    __shared__ float h2s[128];
    float s = b_d1[tid];
    #pragma unroll
    for (int t = 0; t < 28; ++t) s += h1p[(size_t)t * 131072 + b * 256 + tid];
    h1s[tid] = s > 0.f ? s : 0.f;
    __syncthreads();
    if (tid < 128) {
        float s2 = b_d2[tid];
        const float* wp = w_d2 + tid * 256;
        #pragma unroll 4
        for (int k = 0; k < 256; ++k) s2 += h1s[k] * wp[k];
        h2s[tid] = s2 > 0.f ? s2 : 0.f;
    }
    __syncthreads();
    if (tid < 16) {
        float s3 = b_d3[tid];
        const float* wp = w_d3 + tid * 128;
        #pragma unroll 4
        for (int k = 0; k < 128; ++k) s3 += h2s[k] * wp[k];
        out[b * 16 + tid] = s3;
    }
}

// ---------------------------------------------------------------------------
extern "C" void kernel_launch(void* const* d_in, const int* in_sizes, int n_in,
                              void* d_out, int out_size, void* d_ws, size_t ws_size,
                              hipStream_t stream) {
    (void)in_sizes; (void)n_in; (void)out_size; (void)ws_size;
    const float* x     = (const float*)d_in[0];
    const float* w0    = (const float*)d_in[1];
    const float* b0    = (const float*)d_in[2];
    const float* w1    = (const float*)d_in[3];
    const float* b1    = (const float*)d_in[4];
    const float* w2    = (const float*)d_in[5];
    const float* b2    = (const float*)d_in[6];
    const float* wa    = (const float*)d_in[7];
    const float* wb    = (const float*)d_in[8];
    const float* wg    = (const float*)d_in[9];
    const float* wd    = (const float*)d_in[10];
    const float* wenc  = (const float*)d_in[11];
    const float* cw    = (const float*)d_in[12];
    const float* scale = (const float*)d_in[13];
    const float* w_att = (const float*)d_in[14];
    const float* b_att = (const float*)d_in[15];
    const float* bn_g  = (const float*)d_in[16];
    const float* bn_b  = (const float*)d_in[17];
    const float* w_d1  = (const float*)d_in[18];
    const float* b_d1  = (const float*)d_in[19];
    const float* w_d2  = (const float*)d_in[20];
    const float* b_d2  = (const float*)d_in[21];
    const float* w_d3  = (const float*)d_in[22];
    const float* b_d3  = (const float*)d_in[23];

    float* ws    = (float*)d_ws;
    unsigned short* WE1H = (unsigned short*)(ws + OFF_WE1H);
    unsigned short* WE2H = (unsigned short*)(ws + OFF_WE2H);
    unsigned short* WE3H = (unsigned short*)(ws + OFF_WE3H);
    float* TMP   = ws + OFF_C1;     // alias: weff build finishes before conv0 writes C1
    float* C1    = ws + OFF_C1;
    float* C2    = ws + OFF_C2;
    float* XX1   = ws + OFF_XX1;
    float* GAM   = ws + OFF_GAM;
    float* CTX   = ws + OFF_CTX;
    float* H1P   = ws + OFF_H1P;
    float* CTX2  = ws + OFF_CTX2;
    float* XX2   = ws + OFF_XX2;
    float* Z     = ws + OFF_Z;
    float* A     = ws + OFF_A;
    float* E     = ws + OFF_E;
    float* BNS   = ws + OFF_BNS;
    float* XX3   = ws + OFF_XX3;
    float* MS    = ws + OFF_MS;
    unsigned short* WH  = (unsigned short*)(ws + OFF_WH);   // alias ALPHA (dead until abgctx)
    unsigned short* WL  = (unsigned short*)(ws + OFF_WL);
    unsigned short* W1H = (unsigned short*)(ws + OFF_W1H);
    unsigned short* W1L = (unsigned short*)(ws + OFF_W1L);
    unsigned short* W2H = (unsigned short*)(ws + OFF_W2H);
    unsigned short* W2L = (unsigned short*)(ws + OFF_W2L);

    // weight prep (bf16 hi/lo splits, round-6 [s][c][WSTR] layout)
    sac_wsplit<<<504, 256, 0, stream>>>(w0, WH, WL);
    sac_wsplit64<<<144, 256, 0, stream>>>(w1, W1H, W1L);
    sac_wsplit64<<<144, 256, 0, stream>>>(w2, W2H, W2L);

    // fold bilinear upsample into w_d1, emit bf16 weff (hi only; sparse loops)
    sac_upA<<<20672, 256, 0, stream>>>(w_d1, TMP, 17, 0);
    sac_upB_bf16<<<18496, 256, 0, stream>>>(TMP, WE1H, 17);
    sac_upA<<<15808, 256, 0, stream>>>(w_d1, TMP, 13, 64);
    sac_upB_bf16<<<10816, 256, 0, stream>>>(TMP, WE2H, 13);
    sac_upA<<<8512, 256, 0, stream>>>(w_d1, TMP, 7, 128);
    sac_upB_bf16<<<3136, 256, 0, stream>>>(TMP, WE3H, 7);

    // backbone: 3 dilated convs (round-6 measured-best kernels)
    //            <IW, OW, DIL, TOTCH, WSTR, NMT, NIRMAX>
    sac_convmfma<19, 17, 1, 200, 224, 5, 7 ><<<2560, 256, 0, stream>>>(x,  WH,  WL,  b0, C1);
    sac_convmfma<17, 13, 2,  64,  64, 3, 10><<<1536, 256, 0, stream>>>(C1, W1H, W1L, b1, C2);
    sac_convmfma<13,  7, 3,  64,  64, 1, 13><<< 512, 256, 0, stream>>>(C2, W2H, W2L, b2, XX1);

    // non-local block (abg+ctx fused; batch-softmax stats + fused normalize)
    sac_abgctx<<<512, 256, 0, stream>>>(XX1, wa, wb, wg, GAM, CTX);
    sac_smstat<<<76, 256, 0, stream>>>(CTX, MS);
    sac_ctx2<<<512, 256, 0, stream>>>(GAM, CTX, MS, CTX2);
    sac_xx2z<<<512, 256, 0, stream>>>(CTX2, wd, XX1, wenc, XX2, Z);

    // soft VQ encoding + gate (dist+softmax fused; bnstat single-pass)
    sac_dista<<<98, 256, 0, stream>>>(Z, cw, scale, A);
    sac_e<<<512, 256, 0, stream>>>(A, Z, cw, E);
    sac_bnstat<<<48, 256, 0, stream>>>(E, BNS);
    sac_gate<<<512, 256, 0, stream>>>(E, BNS, bn_g, bn_b, w_att, b_att, XX2, XX3);

    // dense head: fine split-K GEMM (64x128 tiles) + fused h1/h2/out
    sac_d1gemm_mfma<<<448, 256, 0, stream>>>(C1, C2, XX3, WE1H, WE2H, WE3H, H1P);
    sac_head<<<512, 256, 0, stream>>>(H1P, b_d1, w_d2, b_d2, w_d3, b_d3, (float*)d_out);
}

// Round 18
// 766.562 us; speedup vs baseline: 1.0173x; 1.0173x over previous
//
#include <hip/hip_runtime.h>
#include <math.h>

// ---------------------------------------------------------------------------
// SACNet forward. conv0/1/2 = round-6 split-bf16 MFMA (measured best, PAIR=1);
// d1 GEMM = A-bf16 x W-bf16 MFMA (64x64, 896 blocks — r16 measured best);
// fused attention/VQ chain; sparse up-fold.
// B=512, IN=200, P=19, CF=64, TF=32, K=48, D=32, NC=16
// ---------------------------------------------------------------------------

typedef __attribute__((ext_vector_type(8))) short short8v;   // 8 bf16
typedef __attribute__((ext_vector_type(4))) float f32x4;

// workspace offsets (in floats)
#define OFF_WE1H  188928u      // 4734976 shorts = 2367488 floats
#define OFF_WE2H  4923904u
#define OFF_WE3H  7692800u
#define OFF_C1    8495616u     // 512*64*289 (TMP aliases this while building weff)
#define OFF_C2    17965568u    // 512*64*169
#define OFF_XX1   23503360u    // 512*64*49
#define OFF_ALPHA 25108992u    // (conv weights alias pre-abg; H1P at dense phase)
#define OFF_BETA  25911808u    // (MS aliases this after sac_abgctx)
#define OFF_GAM   26714624u
#define OFF_CTX   27517440u    // 512*2401
#define OFF_CTX2  28746752u
#define OFF_XX2   29549568u    // 512*3136
#define OFF_Z     31155200u
#define OFF_A     31958016u
#define OFF_E     33162240u
#define OFF_BNS   33948672u
#define OFF_XX3   33948768u

// H1P: 28 x 512 x 256 = 3670016 floats at OFF_ALPHA (dense phase; dead region)
#define OFF_H1P   OFF_ALPHA
// MS (softmax stats 2x2401) at OFF_BETA (dead before d1gemm)
#define OFF_MS    OFF_BETA

// conv weights (round-6 layout):
#define OFF_WH    OFF_ALPHA
#define OFF_WL    (OFF_ALPHA + 64512u)
#define OFF_W1H   (OFF_ALPHA + 129024u)
#define OFF_W1L   (OFF_W1H + 18432u)
#define OFF_W2H   (OFF_W1L + 18432u)
#define OFF_W2L   (OFF_W2H + 18432u)
// ends 25311744 < OFF_BETA. All dead before sac_abgctx.

__device__ __forceinline__ unsigned bf16_rne_bits(float v) {
    unsigned u = __float_as_uint(v);
    return (u + 0x7FFFu + ((u >> 16) & 1u)) >> 16;
}

// -------------------- split w0 into bf16 hi/lo [s][c][224] -----------------
__global__ __launch_bounds__(256) void sac_wsplit(const float* __restrict__ w0,
                                                  unsigned short* __restrict__ WH,
                                                  unsigned short* __restrict__ WL) {
    int idx = blockIdx.x * 256 + threadIdx.x;   // 9*64*224 = 129024
    if (idx >= 129024) return;
    int ic = idx % 224;
    int c  = (idx / 224) % 64;
    int s  = idx / (224 * 64);
    int ky = s / 3, kx = s % 3;
    float v = 0.f;
    if (ic < 200) v = w0[((c * 200 + ic) * 3 + ky) * 3 + kx];
    unsigned hb = bf16_rne_bits(v);
    float hf = __uint_as_float(hb << 16);
    unsigned lb = bf16_rne_bits(v - hf);
    WH[idx] = (unsigned short)hb;
    WL[idx] = (unsigned short)lb;
}

// -------------------- split 64x64x3x3 weights into [s][c][64] --------------
__global__ __launch_bounds__(256) void sac_wsplit64(const float* __restrict__ wsrc,
                                                    unsigned short* __restrict__ WHo,
                                                    unsigned short* __restrict__ WLo) {
    int idx = blockIdx.x * 256 + threadIdx.x;   // 36864
    if (idx >= 36864) return;
    int ic = idx & 63;
    int c  = (idx >> 6) & 63;
    int s  = idx >> 12;
    int ky = s / 3, kx = s - ky * 3;
    float v = wsrc[((c * 64 + ic) * 3 + ky) * 3 + kx];
    unsigned hb = bf16_rne_bits(v);
    float hf = __uint_as_float(hb << 16);
    unsigned lb = bf16_rne_bits(v - hf);
    WHo[idx] = (unsigned short)hb;
    WLo[idx] = (unsigned short)lb;
}

// --------------------- fold bilinear upsample into w_d1 --------------------
// Sparse inner range (skipped terms exact zeros -> bitwise identical).
__global__ __launch_bounds__(256) void sac_upA(const float* __restrict__ w_d1,
                                               float* __restrict__ tmp, int S, int co) {
    int idx = blockIdx.x * 256 + threadIdx.x;
    int total = 256 * 64 * 19 * S;
    if (idx >= total) return;
    int xp = idx % S;
    int j  = (idx / S) % 19;
    int c  = (idx / (S * 19)) % 64;
    int o  = idx / (S * 19 * 64);
    const float* wrow = w_d1 + (size_t)o * 69312 + (size_t)(co + c) * 361 + j * 19;
    float ratio = (float)(S - 1) / 18.0f;
    int ilo = ((xp - 1) * 18) / (S - 1) - 1; if (ilo < 0) ilo = 0;
    int ihi = ((xp + 1) * 18) / (S - 1) + 1; if (ihi > 18) ihi = 18;
    float s = 0.f;
    for (int i = ilo; i <= ihi; ++i) {
        float xs = i * ratio;
        int x0 = (int)floorf(xs);
        float wx = xs - (float)x0;
        int x1 = x0 + 1; if (x1 > S - 1) x1 = S - 1;
        float cf = (xp == x0 ? 1.f - wx : 0.f) + (xp == x1 ? wx : 0.f);
        s += cf * wrow[i];
    }
    tmp[idx] = s;
}
// upB emits bf16 (hi only) weff
__global__ __launch_bounds__(256) void sac_upB_bf16(const float* __restrict__ tmp,
                                                    unsigned short* __restrict__ WEH, int S) {
    int idx = blockIdx.x * 256 + threadIdx.x;
    int total = 256 * 64 * S * S;
    if (idx >= total) return;
    int xp = idx % S;
    int yp = (idx / S) % S;
    int c  = (idx / (S * S)) % 64;
    int o  = idx / (S * S * 64);
    const float* tp = tmp + (((size_t)o * 64 + c) * 19) * S + xp;
    float ratio = (float)(S - 1) / 18.0f;
    int jlo = ((yp - 1) * 18) / (S - 1) - 1; if (jlo < 0) jlo = 0;
    int jhi = ((yp + 1) * 18) / (S - 1) + 1; if (jhi > 18) jhi = 18;
    float s = 0.f;
    for (int j = jlo; j <= jhi; ++j) {
        float ys = j * ratio;
        int y0 = (int)floorf(ys);
        float wy = ys - (float)y0;
        int y1 = y0 + 1; if (y1 > S - 1) y1 = S - 1;
        float cf = (yp == y0 ? 1.f - wy : 0.f) + (yp == y1 ? wy : 0.f);
        s += cf * tp[j * S];
    }
    WEH[idx] = (unsigned short)bf16_rne_bits(s);
}

// ---------------- generic 3x3 dilated conv, split-bf16 MFMA ----------------
// Round-6 structure (measured best).
template<int IW, int OW, int DIL, int TOTCH, int WSTR, int NMT, int NIRMAX>
__global__ __launch_bounds__(256, 4) void sac_convmfma(const float* __restrict__ x,
                                                       const unsigned short* __restrict__ WHp,
                                                       const unsigned short* __restrict__ WLp,
                                                       const float* __restrict__ bias,
                                                       float* __restrict__ out) {
    constexpr int OP = OW * OW;
    constexpr int ISZ = IW * IW;
    constexpr int NCHUNK = WSTR / 32;
    constexpr int NRC = NIRMAX * IW;
    constexpr int RB = (NRC + 31) / 32;
    __shared__ __align__(16) unsigned short XH[NRC * 32 + 64];
    __shared__ __align__(16) unsigned short XL[NRC * 32 + 64];
    int blk = blockIdx.x;
    int b = blk / NMT, mt = blk - b * NMT;
    int tid = threadIdx.x;
    int wv = tid >> 6, l = tid & 63;
    int lh = l >> 5, li = l & 31;
    int wm = wv >> 1, wn = wv & 1;
    int q = l >> 4, r = l & 15;
    int p_base = mt * 64 + wm * 32;
    int n_base = wn * 32;
    int pixA = p_base + r;      if (pixA > OP - 1) pixA = OP - 1;
    int pixB = p_base + 16 + r; if (pixB > OP - 1) pixB = OP - 1;
    int pyA = pixA / OW, pxa = pixA - pyA * OW;
    int pyB = pixB / OW, pxb = pixB - pyB * OW;
    int ir0 = (mt * 64) / OW;
    int rcA0 = (pyA - ir0) * IW + pxa;
    int rcB0 = (pyB - ir0) * IW + pxb;

    f32x4 acc[2][2];
    #pragma unroll
    for (int i = 0; i < 2; ++i)
        #pragma unroll
        for (int j = 0; j < 2; ++j) { acc[i][j].x = 0.f; acc[i][j].y = 0.f; acc[i][j].z = 0.f; acc[i][j].w = 0.f; }

    for (int cc = 0; cc < NCHUNK; ++cc) {
        int ch0 = cc * 32;
        __syncthreads();
        for (int it = wv; it < 4 * RB; it += 4) {
            int cg = it / RB, rb = it - cg * RB;
            int rc = rb * 32 + li;
            if (rc < NRC) {
                int chl4 = cg * 2 + lh;          // 0..7
                int ch = ch0 + chl4 * 4;
                int idx = ir0 * IW + rc; if (idx > ISZ - 1) idx = ISZ - 1;
                const float* gp = x + (size_t)b * (TOTCH * ISZ) + (size_t)ch * ISZ + idx;
                float v0 = (ch + 0 < TOTCH) ? gp[0] : 0.f;
                float v1 = (ch + 1 < TOTCH) ? gp[ISZ] : 0.f;
                float v2 = (ch + 2 < TOTCH) ? gp[2 * ISZ] : 0.f;
                float v3 = (ch + 3 < TOTCH) ? gp[3 * ISZ] : 0.f;
                unsigned h0 = bf16_rne_bits(v0); unsigned l0 = bf16_rne_bits(v0 - __uint_as_float(h0 << 16));
                unsigned h1 = bf16_rne_bits(v1); unsigned l1 = bf16_rne_bits(v1 - __uint_as_float(h1 << 16));
                unsigned h2 = bf16_rne_bits(v2); unsigned l2 = bf16_rne_bits(v2 - __uint_as_float(h2 << 16));
                unsigned h3 = bf16_rne_bits(v3); unsigned l3 = bf16_rne_bits(v3 - __uint_as_float(h3 << 16));
                unsigned bo = ((unsigned)(rc * 64 + chl4 * 8)) ^ (unsigned)((rc & 7) << 4);
                uint2 hv; hv.x = h0 | (h1 << 16); hv.y = h2 | (h3 << 16);
                uint2 lv; lv.x = l0 | (l1 << 16); lv.y = l2 | (l3 << 16);
                *(uint2*)((char*)XH + bo) = hv;
                *(uint2*)((char*)XL + bo) = lv;
            }
        }
        __syncthreads();
        #pragma unroll 3
        for (int s9 = 0; s9 < 9; ++s9) {
            int ky = s9 / 3, kx = s9 - ky * 3;
            int rcA = rcA0 + DIL * (ky * IW + kx);
            int rcB = rcB0 + DIL * (ky * IW + kx);
            unsigned byA = ((unsigned)(rcA * 64 + q * 16)) ^ (unsigned)((rcA & 7) << 4);
            unsigned byB = ((unsigned)(rcB * 64 + q * 16)) ^ (unsigned)((rcB & 7) << 4);
            short8v ah0 = *(const short8v*)((const char*)XH + byA);
            short8v al0 = *(const short8v*)((const char*)XL + byA);
            short8v ah1 = *(const short8v*)((const char*)XH + byB);
            short8v al1 = *(const short8v*)((const char*)XL + byB);
            const unsigned short* pWH = WHp + (size_t)(s9 * 64 + n_base + r) * WSTR + ch0 + q * 8;
            const unsigned short* pWL = WLp + (size_t)(s9 * 64 + n_base + r) * WSTR + ch0 + q * 8;
            short8v bh0 = *(const short8v*)(pWH);
            short8v bh1 = *(const short8v*)(pWH + 16 * WSTR);
            short8v bl0 = *(const short8v*)(pWL);
            short8v bl1 = *(const short8v*)(pWL + 16 * WSTR);
            acc[0][0] = __builtin_amdgcn_mfma_f32_16x16x32_bf16(ah0, bh0, acc[0][0], 0, 0, 0);
            acc[0][1] = __builtin_amdgcn_mfma_f32_16x16x32_bf16(ah0, bh1, acc[0][1], 0, 0, 0);
            acc[1][0] = __builtin_amdgcn_mfma_f32_16x16x32_bf16(ah1, bh0, acc[1][0], 0, 0, 0);
            acc[1][1] = __builtin_amdgcn_mfma_f32_16x16x32_bf16(ah1, bh1, acc[1][1], 0, 0, 0);
            acc[0][0] = __builtin_amdgcn_mfma_f32_16x16x32_bf16(ah0, bl0, acc[0][0], 0, 0, 0);
            acc[0][1] = __builtin_amdgcn_mfma_f32_16x16x32_bf16(ah0, bl1, acc[0][1], 0, 0, 0);
            acc[1][0] = __builtin_amdgcn_mfma_f32_16x16x32_bf16(ah1, bl0, acc[1][0], 0, 0, 0);
            acc[1][1] = __builtin_amdgcn_mfma_f32_16x16x32_bf16(ah1, bl1, acc[1][1], 0, 0, 0);
            acc[0][0] = __builtin_amdgcn_mfma_f32_16x16x32_bf16(al0, bh0, acc[0][0], 0, 0, 0);
            acc[0][1] = __builtin_amdgcn_mfma_f32_16x16x32_bf16(al0, bh1, acc[0][1], 0, 0, 0);
            acc[1][0] = __builtin_amdgcn_mfma_f32_16x16x32_bf16(al1, bh0, acc[1][0], 0, 0, 0);
            acc[1][1] = __builtin_amdgcn_mfma_f32_16x16x32_bf16(al1, bh1, acc[1][1], 0, 0, 0);
        }
    }
    float bias0 = bias[n_base + r];
    float bias1 = bias[n_base + 16 + r];
    #pragma unroll
    for (int mf = 0; mf < 2; ++mf) {
        #pragma unroll
        for (int nf = 0; nf < 2; ++nf) {
            int ch = n_base + nf * 16 + r;
            float bs = nf ? bias1 : bias0;
            float* op = out + ((size_t)b * 64 + ch) * OP;
            #pragma unroll
            for (int j = 0; j < 4; ++j) {
                int pix = p_base + mf * 16 + q * 4 + j;
                if (pix < OP) {
                    float v = acc[mf][nf][j] + bs;
                    op[pix] = v > 0.f ? v : 0.f;
                }
            }
        }
    }
}

// ------- fused: 1x1 convs a/b/g + ctx = alpha(raw reshape) @ beta ----------
__global__ __launch_bounds__(256) void sac_abgctx(const float* __restrict__ xx1,
                                                  const float* __restrict__ wa,
                                                  const float* __restrict__ wb,
                                                  const float* __restrict__ wg,
                                                  float* __restrict__ gam,
                                                  float* __restrict__ ctx) {
    int b = blockIdx.x, tid = threadIdx.x;
    __shared__ float xsm[3136];
    __shared__ float ws3[3 * 2048];
    __shared__ float ab[3136];          // alpha[0..1568) beta[1568..3136)
    for (int f = tid; f < 3136; f += 256) xsm[f] = xx1[(size_t)b * 3136 + f];
    for (int f = tid; f < 2048; f += 256) {
        ws3[f] = wa[f]; ws3[2048 + f] = wb[f]; ws3[4096 + f] = wg[f];
    }
    __syncthreads();
    for (int f = tid; f < 4704; f += 256) {
        int which = f / 1568, r = f - which * 1568;
        int t = r / 49, p = r - t * 49;
        const float* w = &ws3[which * 2048 + t * 64];
        float s = 0.f;
        #pragma unroll 8
        for (int c = 0; c < 64; ++c) s += w[c] * xsm[c * 49 + p];
        if (which == 2) {
            s = s > 0.f ? s : 0.f;
            gam[(size_t)b * 1568 + r] = s;
        } else {
            ab[which * 1568 + r] = s;
        }
    }
    __syncthreads();
    for (int f = tid; f < 2401; f += 256) {
        int i = f / 49, lcol = f - i * 49;
        float s = 0.f;
        #pragma unroll 8
        for (int j = 0; j < 32; ++j) s += ab[i * 32 + j] * ab[1568 + j * 49 + lcol];
        ctx[(size_t)b * 2401 + f] = s;
    }
}

// -------- softmax-over-batch stats: MS[pos]=max, MS[2401+pos]=1/sum --------
__global__ __launch_bounds__(256) void sac_smstat(const float* __restrict__ ctx,
                                                  float* __restrict__ ms) {
    __shared__ float red[8][32];
    int tid = threadIdx.x;
    int pl = tid & 31, g = tid >> 5;
    int pos = blockIdx.x * 32 + pl;
    bool ok = pos < 2401;
    float m = -1e30f;
    if (ok) for (int b = g; b < 512; b += 8) m = fmaxf(m, ctx[(size_t)b * 2401 + pos]);
    red[g][pl] = m;
    __syncthreads();
    if (g == 0) {
        #pragma unroll
        for (int t = 1; t < 8; ++t) m = fmaxf(m, red[t][pl]);
        red[0][pl] = m;
    }
    __syncthreads();
    m = red[0][pl];
    float s = 0.f;
    if (ok) for (int b = g; b < 512; b += 8) s += expf(ctx[(size_t)b * 2401 + pos] - m);
    __syncthreads();
    red[g][pl] = s;
    __syncthreads();
    if (g == 0 && ok) {
        #pragma unroll
        for (int t = 1; t < 8; ++t) s += red[t][pl];
        ms[pos] = m;
        ms[2401 + pos] = 1.f / s;
    }
}

// ---------------- ctx2 = gam @ softmax0(ctx) (normalize fused) -------------
__global__ __launch_bounds__(256) void sac_ctx2(const float* __restrict__ gam,
                                                const float* __restrict__ ctx,
                                                const float* __restrict__ ms,
                                                float* __restrict__ ctx2) {
    int b = blockIdx.x, tid = threadIdx.x;
    __shared__ float gs[1568];
    __shared__ float cs[2401];
    for (int f = tid; f < 1568; f += 256) gs[f] = gam[(size_t)b * 1568 + f];
    for (int f = tid; f < 2401; f += 256)
        cs[f] = expf(ctx[(size_t)b * 2401 + f] - ms[f]) * ms[2401 + f];
    __syncthreads();
    for (int f = tid; f < 1568; f += 256) {
        int t = f / 49, lcol = f - t * 49;
        float s = 0.f;
        #pragma unroll 7
        for (int i = 0; i < 49; ++i) s += gs[t * 49 + i] * cs[i * 49 + lcol];
        ctx2[(size_t)b * 1568 + f] = s;
    }
}

// -------- fused: xx2 = relu(wd @ ctx2) + xx1 ; Z = relu(wenc @ xx2) --------
__global__ __launch_bounds__(256) void sac_xx2z(const float* __restrict__ ctx2,
                                                const float* __restrict__ wd,
                                                const float* __restrict__ xx1,
                                                const float* __restrict__ wenc,
                                                float* __restrict__ xx2,
                                                float* __restrict__ Z) {
    int b = blockIdx.x, tid = threadIdx.x;
    __shared__ float cs[1568];
    __shared__ float wds[2048];
    __shared__ float xs2[3136];
    __shared__ float wt[2048];   // [c][d]
    for (int f = tid; f < 1568; f += 256) cs[f] = ctx2[(size_t)b * 1568 + f];
    for (int f = tid; f < 2048; f += 256) {
        wds[f] = wd[f];
        int d = f >> 6, c = f & 63; wt[c * 32 + d] = wenc[f];
    }
    __syncthreads();
    for (int f = tid; f < 3136; f += 256) {
        int c = f / 49, p = f - c * 49;
        float s = 0.f;
        #pragma unroll 8
        for (int t = 0; t < 32; ++t) s += wds[c * 32 + t] * cs[t * 49 + p];
        s = s > 0.f ? s : 0.f;
        s += xx1[(size_t)b * 3136 + f];
        xs2[f] = s;
        xx2[(size_t)b * 3136 + f] = s;
    }
    __syncthreads();
    for (int f = tid; f < 1568; f += 256) {
        int p = f >> 5, d = f & 31;
        float s = 0.f;
        #pragma unroll 8
        for (int c = 0; c < 64; ++c) s += wt[c * 32 + d] * xs2[c * 49 + p];
        Z[(size_t)b * 1568 + f] = s > 0.f ? s : 0.f;
    }
}

// -------------- dist + softmax over k (48), fused in-register --------------
__global__ __launch_bounds__(256) void sac_dista(const float* __restrict__ Z,
                                                 const float* __restrict__ cw,
                                                 const float* __restrict__ scale,
                                                 float* __restrict__ A) {
    __shared__ float cws[1536];
    __shared__ float c2s[48];
    __shared__ float scs[48];
    int tid = threadIdx.x;
    for (int f = tid; f < 1536; f += 256) cws[f] = cw[f];
    if (tid < 48) scs[tid] = scale[tid];
    __syncthreads();
    if (tid < 48) {
        float s = 0.f;
        for (int d = 0; d < 32; ++d) { float v = cws[tid * 32 + d]; s += v * v; }
        c2s[tid] = s;
    }
    __syncthreads();
    int idx = blockIdx.x * 256 + tid;      // (b,p) over 25088
    if (idx >= 25088) return;
    const float4* zp = (const float4*)(Z + (size_t)idx * 32);
    float zr[32];
    #pragma unroll
    for (int q = 0; q < 8; ++q) {
        float4 v = zp[q];
        zr[q * 4] = v.x; zr[q * 4 + 1] = v.y; zr[q * 4 + 2] = v.z; zr[q * 4 + 3] = v.w;
    }
    float z2 = 0.f;
    #pragma unroll
    for (int d = 0; d < 32; ++d) z2 += zr[d] * zr[d];
    float v48[48];
    float m = -1e30f;
    for (int k = 0; k < 48; ++k) {
        float dot = 0.f;
        #pragma unroll
        for (int d = 0; d < 32; ++d) dot += zr[d] * cws[k * 32 + d];
        float dv = scs[k] * (z2 + c2s[k] - 2.f * dot);
        v48[k] = dv;
        m = fmaxf(m, dv);
    }
    float s = 0.f;
    #pragma unroll
    for (int k = 0; k < 48; ++k) { v48[k] = expf(v48[k] - m); s += v48[k]; }
    float inv = 1.f / s;
    float* ap = A + (size_t)idx * 48;
    #pragma unroll
    for (int k = 0; k < 48; ++k) ap[k] = v48[k] * inv;
}

// ------------- E[b,k,d] = sum_p A*Z - (sum_p A) * C ------------------------
__global__ __launch_bounds__(256) void sac_e(const float* __restrict__ A,
                                             const float* __restrict__ Z,
                                             const float* __restrict__ cw,
                                             float* __restrict__ E) {
    int b = blockIdx.x, tid = threadIdx.x;
    __shared__ float As[2352];
    __shared__ float Zs[1568];
    __shared__ float asum[48];
    for (int f = tid; f < 2352; f += 256) As[f] = A[(size_t)b * 2352 + f];
    for (int f = tid; f < 1568; f += 256) Zs[f] = Z[(size_t)b * 1568 + f];
    __syncthreads();
    if (tid < 48) {
        float s = 0.f;
        for (int p = 0; p < 49; ++p) s += As[p * 48 + tid];
        asum[tid] = s;
    }
    __syncthreads();
    for (int f = tid; f < 1536; f += 256) {
        int k = f >> 5, d = f & 31;
        float s = 0.f;
        #pragma unroll 7
        for (int p = 0; p < 49; ++p) s += As[p * 48 + k] * Zs[p * 32 + d];
        E[(size_t)b * 1536 + f] = s - asum[k] * cw[f];
    }
}

// --------- BatchNorm stats per code k (single pass: sum + sumsq) -----------
__global__ __launch_bounds__(256) void sac_bnstat(const float* __restrict__ E,
                                                  float* __restrict__ bns) {
    int k = blockIdx.x, tid = threadIdx.x;
    __shared__ float sr[4], qr[4];
    float s = 0.f, q = 0.f;
    for (int i = tid; i < 16384; i += 256) {
        int b = i >> 5, d = i & 31;
        float v = E[((size_t)b * 48 + k) * 32 + d];
        s += v;
        q += v * v;
    }
    #pragma unroll
    for (int off = 32; off > 0; off >>= 1) {
        s += __shfl_xor(s, off, 64);
        q += __shfl_xor(q, off, 64);
    }
    int lane = tid & 63, wid = tid >> 6;
    if (lane == 0) { sr[wid] = s; qr[wid] = q; }
    __syncthreads();
    if (tid == 0) {
        float mu = (sr[0] + sr[1] + sr[2] + sr[3]) / 16384.f;
        float ms2 = (qr[0] + qr[1] + qr[2] + qr[3]) / 16384.f;
        float var = ms2 - mu * mu;
        if (var < 0.f) var = 0.f;
        bns[k] = mu;
        bns[48 + k] = rsqrtf(var + 1e-5f);
    }
}

// ---------------- BN+relu -> E_sum -> gate -> xx3 --------------------------
__global__ __launch_bounds__(256) void sac_gate(const float* __restrict__ E,
                                                const float* __restrict__ bns,
                                                const float* __restrict__ bn_g,
                                                const float* __restrict__ bn_b,
                                                const float* __restrict__ w_att,
                                                const float* __restrict__ b_att,
                                                const float* __restrict__ xx2,
                                                float* __restrict__ xx3) {
    int b = blockIdx.x, tid = threadIdx.x;
    __shared__ float esd[32];
    __shared__ float gs[64];
    if (tid < 32) {
        int d = tid;
        float s = 0.f;
        for (int k = 0; k < 48; ++k) {
            float v = (E[((size_t)b * 48 + k) * 32 + d] - bns[k]) * bns[48 + k] * bn_g[k] + bn_b[k];
            s += v > 0.f ? v : 0.f;
        }
        esd[d] = s;
    }
    __syncthreads();
    if (tid < 64) {
        int c = tid;
        float a = b_att[c];
        #pragma unroll 8
        for (int d = 0; d < 32; ++d) a += esd[d] * w_att[c * 32 + d];
        gs[c] = 1.f / (1.f + expf(-a)) + 1.f;     // 1 + gate
    }
    __syncthreads();
    for (int f = tid; f < 3136; f += 256) {
        int c = f / 49;
        xx3[(size_t)b * 3136 + f] = xx2[(size_t)b * 3136 + f] * gs[c];
    }
}

// ------- d1 GEMM: A=bf16 x W=bf16 MFMA, fine split-K (64x64, r16 best) -----
__global__ __launch_bounds__(256, 4) void sac_d1gemm_mfma(const float* __restrict__ c1,
                                                          const float* __restrict__ c2,
                                                          const float* __restrict__ xx3,
                                                          const unsigned short* __restrict__ we1h,
                                                          const unsigned short* __restrict__ we2h,
                                                          const unsigned short* __restrict__ we3h,
                                                          float* __restrict__ h1p) {
    constexpr int KCH = 128;
    __shared__ unsigned short AH[64 * KCH + 64];
    int blk = blockIdx.x;
    int g = blk >> 5, r5 = blk & 31;
    int b0 = (r5 >> 2) * 64, o0 = (r5 & 3) * 64;
    const float* Ab; const unsigned short *WHb; int astr, klen, kbase;
    if (g < 16)      { int slab = g >> 2, kq4 = g & 3;
                       Ab = c1;  WHb = we1h; astr = 18496; klen = 1156; kbase = slab * 4624 + kq4 * 1156; }
    else if (g < 24) { int gg = g - 16; int slab = gg >> 2, kq4 = gg & 3;
                       Ab = c2;  WHb = we2h; astr = 10816; klen = 1352; kbase = slab * 5408 + kq4 * 1352; }
    else             { int kq4 = g - 24;
                       Ab = xx3; WHb = we3h; astr = 3136;  klen = 784;  kbase = kq4 * 784; }
    int tid = threadIdx.x;
    int w = tid >> 6, l = tid & 63;
    int wm = w >> 1, wn = w & 1;
    int q = l >> 4, r = l & 15;

    f32x4 acc[2][2];
    #pragma unroll
    for (int i = 0; i < 2; ++i)
        #pragma unroll
        for (int j = 0; j < 2; ++j) { acc[i][j].x = 0.f; acc[i][j].y = 0.f; acc[i][j].z = 0.f; acc[i][j].w = 0.f; }

    int nkch = (klen + KCH - 1) / KCH;
    for (int kc = 0; kc < nkch; ++kc) {
        int k0 = kc * KCH;
        __syncthreads();
        for (int f = tid; f < 64 * (KCH / 2); f += 256) {
            int row = f >> 6, col2 = (f & 63) << 1;
            int kk = k0 + col2;
            float va = 0.f, vb = 0.f;
            if (kk < klen) {
                float2 v = *(const float2*)(Ab + (size_t)(b0 + row) * astr + kbase + kk);
                va = v.x; vb = v.y;
            }
            unsigned h0 = bf16_rne_bits(va);
            unsigned h1 = bf16_rne_bits(vb);
            unsigned bo = ((unsigned)(row * 256 + col2 * 2)) ^ (unsigned)((row & 7) << 4);
            *(unsigned*)((char*)AH + bo) = h0 | (h1 << 16);
        }
        __syncthreads();
        #pragma unroll
        for (int ks = 0; ks < KCH / 32; ++ks) {
            int k = ks * 32 + q * 8;
            int rowA0 = wm * 32 + r, rowA1 = wm * 32 + 16 + r;
            unsigned byA0 = ((unsigned)(rowA0 * 256 + k * 2)) ^ (unsigned)((rowA0 & 7) << 4);
            unsigned byA1 = ((unsigned)(rowA1 * 256 + k * 2)) ^ (unsigned)((rowA1 & 7) << 4);
            short8v ah0 = *(const short8v*)((const char*)AH + byA0);
            short8v ah1 = *(const short8v*)((const char*)AH + byA1);
            size_t wofs = (size_t)(o0 + wn * 32 + r) * astr + kbase + k0 + k;
            short8v bh0 = *(const short8v*)(WHb + wofs);
            short8v bh1 = *(const short8v*)(WHb + wofs + (size_t)16 * astr);
            acc[0][0] = __builtin_amdgcn_mfma_f32_16x16x32_bf16(ah0, bh0, acc[0][0], 0, 0, 0);
            acc[0][1] = __builtin_amdgcn_mfma_f32_16x16x32_bf16(ah0, bh1, acc[0][1], 0, 0, 0);
            acc[1][0] = __builtin_amdgcn_mfma_f32_16x16x32_bf16(ah1, bh0, acc[1][0], 0, 0, 0);
            acc[1][1] = __builtin_amdgcn_mfma_f32_16x16x32_bf16(ah1, bh1, acc[1][1], 0, 0, 0);
        }
    }
    #pragma unroll
    for (int mf = 0; mf < 2; ++mf) {
        #pragma unroll
        for (int nf = 0; nf < 2; ++nf) {
            int o = o0 + wn * 32 + nf * 16 + r;
            #pragma unroll
            for (int j = 0; j < 4; ++j) {
                int batch = b0 + wm * 32 + mf * 16 + q * 4 + j;
                h1p[((size_t)g * 512 + batch) * 256 + o] = acc[mf][nf][j];
            }
        }
    }
}

// ----- fused head: h1 = relu(sum 28 partials + b1); h2 = relu(.); out ------
__global__ __launch_bounds__(256) void sac_head(const float* __restrict__ h1p,
                                                const float* __restrict__ b_d1,
                                                const float* __restrict__ w_d2,
                                                const float* __restrict__ b_d2,
                                                const float* __restrict__ w_d3,
                                                const float* __restrict__ b_d3,
                                                float* __restrict__ out) {
    int b = blockIdx.x, tid = threadIdx.x;
    __shared__ float h1s[256];
    __shared__ float h2s[128];
    float s = b_d1[tid];
    #pragma unroll
    for (int t = 0; t < 28; ++t) s += h1p[(size_t)t * 131072 + b * 256 + tid];
    h1s[tid] = s > 0.f ? s : 0.f;
    __syncthreads();
    if (tid < 128) {
        float s2 = b_d2[tid];
        const float* wp = w_d2 + tid * 256;
        #pragma unroll 4
        for (int k = 0; k < 256; ++k) s2 += h1s[k] * wp[k];
        h2s[tid] = s2 > 0.f ? s2 : 0.f;
    }
    __syncthreads();
    if (tid < 16) {
        float s3 = b_d3[tid];
        const float* wp = w_d3 + tid * 128;
        #pragma unroll 4
        for (int k = 0; k < 128; ++k) s3 += h2s[k] * wp[k];
        out[b * 16 + tid] = s3;
    }
}

// ---------------------------------------------------------------------------
extern "C" void kernel_launch(void* const* d_in, const int* in_sizes, int n_in,
                              void* d_out, int out_size, void* d_ws, size_t ws_size,
                              hipStream_t stream) {
    (void)in_sizes; (void)n_in; (void)out_size; (void)ws_size;
    const float* x     = (const float*)d_in[0];
    const float* w0    = (const float*)d_in[1];
    const float* b0    = (const float*)d_in[2];
    const float* w1    = (const float*)d_in[3];
    const float* b1    = (const float*)d_in[4];
    const float* w2    = (const float*)d_in[5];
    const float* b2    = (const float*)d_in[6];
    const float* wa    = (const float*)d_in[7];
    const float* wb    = (const float*)d_in[8];
    const float* wg    = (const float*)d_in[9];
    const float* wd    = (const float*)d_in[10];
    const float* wenc  = (const float*)d_in[11];
    const float* cw    = (const float*)d_in[12];
    const float* scale = (const float*)d_in[13];
    const float* w_att = (const float*)d_in[14];
    const float* b_att = (const float*)d_in[15];
    const float* bn_g  = (const float*)d_in[16];
    const float* bn_b  = (const float*)d_in[17];
    const float* w_d1  = (const float*)d_in[18];
    const float* b_d1  = (const float*)d_in[19];
    const float* w_d2  = (const float*)d_in[20];
    const float* b_d2  = (const float*)d_in[21];
    const float* w_d3  = (const float*)d_in[22];
    const float* b_d3  = (const float*)d_in[23];

    float* ws    = (float*)d_ws;
    unsigned short* WE1H = (unsigned short*)(ws + OFF_WE1H);
    unsigned short* WE2H = (unsigned short*)(ws + OFF_WE2H);
    unsigned short* WE3H = (unsigned short*)(ws + OFF_WE3H);
    float* TMP   = ws + OFF_C1;     // alias: weff build finishes before conv0 writes C1
    float* C1    = ws + OFF_C1;
    float* C2    = ws + OFF_C2;
    float* XX1   = ws + OFF_XX1;
    float* GAM   = ws + OFF_GAM;
    float* CTX   = ws + OFF_CTX;
    float* H1P   = ws + OFF_H1P;
    float* CTX2  = ws + OFF_CTX2;
    float* XX2   = ws + OFF_XX2;
    float* Z     = ws + OFF_Z;
    float* A     = ws + OFF_A;
    float* E     = ws + OFF_E;
    float* BNS   = ws + OFF_BNS;
    float* XX3   = ws + OFF_XX3;
    float* MS    = ws + OFF_MS;
    unsigned short* WH  = (unsigned short*)(ws + OFF_WH);   // alias ALPHA (dead until abgctx)
    unsigned short* WL  = (unsigned short*)(ws + OFF_WL);
    unsigned short* W1H = (unsigned short*)(ws + OFF_W1H);
    unsigned short* W1L = (unsigned short*)(ws + OFF_W1L);
    unsigned short* W2H = (unsigned short*)(ws + OFF_W2H);
    unsigned short* W2L = (unsigned short*)(ws + OFF_W2L);

    // weight prep (bf16 hi/lo splits, round-6 [s][c][WSTR] layout)
    sac_wsplit<<<504, 256, 0, stream>>>(w0, WH, WL);
    sac_wsplit64<<<144, 256, 0, stream>>>(w1, W1H, W1L);
    sac_wsplit64<<<144, 256, 0, stream>>>(w2, W2H, W2L);

    // fold bilinear upsample into w_d1, emit bf16 weff (hi only; sparse loops)
    sac_upA<<<20672, 256, 0, stream>>>(w_d1, TMP, 17, 0);
    sac_upB_bf16<<<18496, 256, 0, stream>>>(TMP, WE1H, 17);
    sac_upA<<<15808, 256, 0, stream>>>(w_d1, TMP, 13, 64);
    sac_upB_bf16<<<10816, 256, 0, stream>>>(TMP, WE2H, 13);
    sac_upA<<<8512, 256, 0, stream>>>(w_d1, TMP, 7, 128);
    sac_upB_bf16<<<3136, 256, 0, stream>>>(TMP, WE3H, 7);

    // backbone: 3 dilated convs (round-6 measured-best kernels, PAIR=1)
    //            <IW, OW, DIL, TOTCH, WSTR, NMT, NIRMAX>
    sac_convmfma<19, 17, 1, 200, 224, 5, 7 ><<<2560, 256, 0, stream>>>(x,  WH,  WL,  b0, C1);
    sac_convmfma<17, 13, 2,  64,  64, 3, 10><<<1536, 256, 0, stream>>>(C1, W1H, W1L, b1, C2);
    sac_convmfma<13,  7, 3,  64,  64, 1, 13><<< 512, 256, 0, stream>>>(C2, W2H, W2L, b2, XX1);

    // non-local block (abg+ctx fused; batch-softmax stats + fused normalize)
    sac_abgctx<<<512, 256, 0, stream>>>(XX1, wa, wb, wg, GAM, CTX);
    sac_smstat<<<76, 256, 0, stream>>>(CTX, MS);
    sac_ctx2<<<512, 256, 0, stream>>>(GAM, CTX, MS, CTX2);
    sac_xx2z<<<512, 256, 0, stream>>>(CTX2, wd, XX1, wenc, XX2, Z);

    // soft VQ encoding + gate (dist+softmax fused; bnstat single-pass)
    sac_dista<<<98, 256, 0, stream>>>(Z, cw, scale, A);
    sac_e<<<512, 256, 0, stream>>>(A, Z, cw, E);
    sac_bnstat<<<48, 256, 0, stream>>>(E, BNS);
    sac_gate<<<512, 256, 0, stream>>>(E, BNS, bn_g, bn_b, w_att, b_att, XX2, XX3);

    // dense head: fine split-K GEMM (64x64, 896 blocks) + fused h1/h2/out
    sac_d1gemm_mfma<<<896, 256, 0, stream>>>(C1, C2, XX3, WE1H, WE2H, WE3H, H1P);
    sac_head<<<512, 256, 0, stream>>>(H1P, b_d1, w_d2, b_d2, w_d3, b_d3, (float*)d_out);
}